// Round 4
// baseline (216.451 us; speedup 1.0000x reference)
//
#include <hip/hip_runtime.h>

// IntraAgg: out[b] = concat(mean_k E[idx[b,k]], self[b] - mean)
// B=50000, K=32, D=128.
// Phase 1: convert embedding table fp32 -> fp8 e4m3 (OCP) into d_ws.
//          Row shrinks 512B -> 128B = one L2/L3 line per gather.
// Phase 2: gather-mean from fp8 table, 16 lanes/row, 8B/lane loads
//          (16*8B = 128B = full fp8 row, coalesced). HW v_cvt_pk_f32_fp8
//          decode, f32x2 accumulators (v_pk_add_f32).
//          Software-pipelined: loads issued in groups of 8, one group
//          always in flight ahead of decode; __launch_bounds__(256,8)
//          pins VGPR<=64 so 8 waves/SIMD occupancy is guaranteed.
// Evidence trail:
//   R1: nt stores -> 5.4x HBM write amplification + L3 table eviction. Removed.
//   R2: packed adds neutral -> gather not VALU-bound.
//   R3: 8->16 lanes/row (occupancy 6.1->8 waves/SIMD): -8.4 us -> gather is
//       concurrency-limited on random-line fetches (~3.1 TB/s effective).
//   R4 (this): raise per-thread MLP via explicit load pipeline; bytes,
//       lines, numerics unchanged.

constexpr int D = 128;
constexpr int K = 32;
constexpr int ROW_WORDS = D / 4;   // 32 u32 words per fp8 row

typedef float f32x2 __attribute__((ext_vector_type(2)));

// ---------- Phase 1: fp32 -> fp8 e4m3 table conversion ----------
__global__ __launch_bounds__(256) void convert_f32_to_fp8(
    const float* __restrict__ in, unsigned int* __restrict__ out, int n16)
{
    int i = blockIdx.x * blockDim.x + threadIdx.x;   // each thread: 16 floats
    if (i >= n16) return;
    const float4* p = reinterpret_cast<const float4*>(in) + (size_t)i * 4;
    float4 a = p[0], b = p[1], c = p[2], d = p[3];
    unsigned int w0 = 0, w1 = 0, w2 = 0, w3 = 0;
    w0 = __builtin_amdgcn_cvt_pk_fp8_f32(a.x, a.y, w0, false);
    w0 = __builtin_amdgcn_cvt_pk_fp8_f32(a.z, a.w, w0, true);
    w1 = __builtin_amdgcn_cvt_pk_fp8_f32(b.x, b.y, w1, false);
    w1 = __builtin_amdgcn_cvt_pk_fp8_f32(b.z, b.w, w1, true);
    w2 = __builtin_amdgcn_cvt_pk_fp8_f32(c.x, c.y, w2, false);
    w2 = __builtin_amdgcn_cvt_pk_fp8_f32(c.z, c.w, w2, true);
    w3 = __builtin_amdgcn_cvt_pk_fp8_f32(d.x, d.y, w3, false);
    w3 = __builtin_amdgcn_cvt_pk_fp8_f32(d.z, d.w, w3, true);
    uint4 pack; pack.x = w0; pack.y = w1; pack.z = w2; pack.w = w3;
    reinterpret_cast<uint4*>(out)[i] = pack;
}

// ---------- Phase 2: gather-mean, 16 lanes/row, pipelined loads ----------
__global__ __launch_bounds__(256, 8) void intra_agg_fp8(
    const unsigned int* __restrict__ emb,   // fp8 table, 32 words/row
    const float* __restrict__ self_feats,
    const int*   __restrict__ neighbor_idx,
    float*       __restrict__ out,
    int B)
{
    const int tid  = blockIdx.x * blockDim.x + threadIdx.x;
    const int row  = tid >> 4;          // 16 lanes per row
    const int lane = tid & 15;
    if (row >= B) return;

    // Each lane preloads 2 of the 32 indices; broadcast within 16-lane segment.
    const int* ip = neighbor_idx + (size_t)row * K;
    const int iA = ip[lane];
    const int iB = ip[lane + 16];
    const unsigned int* base = emb + lane * 2;   // lane's 8-fp8 column slice

    // Lane owns float columns [lane*8, lane*8+8): 4 f32x2 accumulators.
    f32x2 acc[4];
    #pragma unroll
    for (int j = 0; j < 4; ++j) acc[j] = (f32x2){0.f, 0.f};

    // Two 8-load groups in flight alternately. All indices compile-time
    // after unrolling (no scratch). Group g covers k = 4g .. 4g+3, with
    // loads for neighbors k and k+16.
    uint2 bufA[8], bufB[8];

    // Prologue: issue group 0.
    #pragma unroll
    for (int k = 0; k < 4; ++k) {
        const int a = __shfl(iA, k, 16);
        const int b = __shfl(iB, k, 16);
        bufA[2*k+0] = *reinterpret_cast<const uint2*>(base + (size_t)a * ROW_WORDS);
        bufA[2*k+1] = *reinterpret_cast<const uint2*>(base + (size_t)b * ROW_WORDS);
    }

    #pragma unroll
    for (int g = 0; g < 4; ++g) {
        // Issue next group before decoding current (keeps >=8 loads in flight).
        if (g < 3) {
            #pragma unroll
            for (int k = 0; k < 4; ++k) {
                const int kk = (g + 1) * 4 + k;
                const int a = __shfl(iA, kk, 16);
                const int b = __shfl(iB, kk, 16);
                uint2 va = *reinterpret_cast<const uint2*>(base + (size_t)a * ROW_WORDS);
                uint2 vb = *reinterpret_cast<const uint2*>(base + (size_t)b * ROW_WORDS);
                if (g & 1) { bufA[2*k+0] = va; bufA[2*k+1] = vb; }
                else       { bufB[2*k+0] = va; bufB[2*k+1] = vb; }
            }
        }
        // Decode current group.
        #pragma unroll
        for (int k = 0; k < 4; ++k) {
            const uint2 ea = (g & 1) ? bufB[2*k+0] : bufA[2*k+0];
            const uint2 eb = (g & 1) ? bufB[2*k+1] : bufA[2*k+1];
            acc[0] += __builtin_amdgcn_cvt_pk_f32_fp8(ea.x, false);
            acc[1] += __builtin_amdgcn_cvt_pk_f32_fp8(ea.x, true );
            acc[2] += __builtin_amdgcn_cvt_pk_f32_fp8(ea.y, false);
            acc[3] += __builtin_amdgcn_cvt_pk_f32_fp8(ea.y, true );
            acc[0] += __builtin_amdgcn_cvt_pk_f32_fp8(eb.x, false);
            acc[1] += __builtin_amdgcn_cvt_pk_f32_fp8(eb.x, true );
            acc[2] += __builtin_amdgcn_cvt_pk_f32_fp8(eb.y, false);
            acc[3] += __builtin_amdgcn_cvt_pk_f32_fp8(eb.y, true );
        }
    }

    const float inv = 1.0f / (float)K;
    const int c0 = lane * 8;            // float column base (8 floats/lane)
    const float4* sp = reinterpret_cast<const float4*>(self_feats + (size_t)row * D + c0);
    float* orow = out + (size_t)row * (2 * D);
    float4* om = reinterpret_cast<float4*>(orow + c0);
    float4* od = reinterpret_cast<float4*>(orow + D + c0);

    #pragma unroll
    for (int q = 0; q < 2; ++q) {
        float4 m;
        m.x = acc[2*q + 0].x * inv;
        m.y = acc[2*q + 0].y * inv;
        m.z = acc[2*q + 1].x * inv;
        m.w = acc[2*q + 1].y * inv;
        const float4 s = sp[q];
        float4 dd;
        dd.x = s.x - m.x; dd.y = s.y - m.y; dd.z = s.z - m.z; dd.w = s.w - m.w;
        om[q] = m;
        od[q] = dd;
    }
}

// ---------- Fallback fp32 gather (if ws too small) ----------
__global__ __launch_bounds__(256) void intra_agg_f32(
    const float* __restrict__ embedding,
    const float* __restrict__ self_feats,
    const int*   __restrict__ neighbor_idx,
    float*       __restrict__ out,
    int B)
{
    const int tid    = blockIdx.x * blockDim.x + threadIdx.x;
    const int row    = tid >> 5;
    const int lane32 = tid & 31;
    if (row >= B) return;

    const int my_idx = neighbor_idx[(size_t)row * K + lane32];
    const int c = lane32 * 4;

    float4 a0 = {0,0,0,0}, a1 = {0,0,0,0}, a2 = {0,0,0,0}, a3 = {0,0,0,0};
    #pragma unroll
    for (int k = 0; k < K; k += 4) {
        const int i0 = __shfl(my_idx, k + 0, 32);
        const int i1 = __shfl(my_idx, k + 1, 32);
        const int i2 = __shfl(my_idx, k + 2, 32);
        const int i3 = __shfl(my_idx, k + 3, 32);
        const float4 e0 = *reinterpret_cast<const float4*>(embedding + (size_t)i0 * D + c);
        const float4 e1 = *reinterpret_cast<const float4*>(embedding + (size_t)i1 * D + c);
        const float4 e2 = *reinterpret_cast<const float4*>(embedding + (size_t)i2 * D + c);
        const float4 e3 = *reinterpret_cast<const float4*>(embedding + (size_t)i3 * D + c);
        a0.x += e0.x; a0.y += e0.y; a0.z += e0.z; a0.w += e0.w;
        a1.x += e1.x; a1.y += e1.y; a1.z += e1.z; a1.w += e1.w;
        a2.x += e2.x; a2.y += e2.y; a2.z += e2.z; a2.w += e2.w;
        a3.x += e3.x; a3.y += e3.y; a3.z += e3.z; a3.w += e3.w;
    }

    const float inv = 1.0f / (float)K;
    float4 mean;
    mean.x = (a0.x + a1.x + a2.x + a3.x) * inv;
    mean.y = (a0.y + a1.y + a2.y + a3.y) * inv;
    mean.z = (a0.z + a1.z + a2.z + a3.z) * inv;
    mean.w = (a0.w + a1.w + a2.w + a3.w) * inv;

    const float4 self = *reinterpret_cast<const float4*>(self_feats + (size_t)row * D + c);
    float4 diff;
    diff.x = self.x - mean.x; diff.y = self.y - mean.y;
    diff.z = self.z - mean.z; diff.w = self.w - mean.w;

    float* orow = out + (size_t)row * (2 * D);
    *reinterpret_cast<float4*>(orow + c)     = mean;
    *reinterpret_cast<float4*>(orow + D + c) = diff;
}

extern "C" void kernel_launch(void* const* d_in, const int* in_sizes, int n_in,
                              void* d_out, int out_size, void* d_ws, size_t ws_size,
                              hipStream_t stream) {
    const float* embedding  = (const float*)d_in[0];
    const float* self_feats = (const float*)d_in[1];
    const int*   neigh_idx  = (const int*)d_in[2];
    float* out = (float*)d_out;

    const int n_embed_elems = in_sizes[0];          // 200000*128
    const int B = in_sizes[1] / D;                  // 50000
    const size_t fp8_bytes = (size_t)n_embed_elems; // 1 byte/elem

    if (ws_size >= fp8_bytes) {
        unsigned int* emb8 = (unsigned int*)d_ws;
        // Phase 1: convert table (16 floats / thread)
        {
            const int n16 = n_embed_elems / 16;
            const int block = 256;
            const int grid = (n16 + block - 1) / block;
            convert_f32_to_fp8<<<grid, block, 0, stream>>>(embedding, emb8, n16);
        }
        // Phase 2: gather-mean (16 lanes / row)
        {
            const long long total_threads = (long long)B * 16;
            const int block = 256;
            const int grid = (int)((total_threads + block - 1) / block);
            intra_agg_fp8<<<grid, block, 0, stream>>>(emb8, self_feats, neigh_idx, out, B);
        }
    } else {
        const long long total_threads = (long long)B * 32;
        const int block = 256;
        const int grid = (int)((total_threads + block - 1) / block);
        intra_agg_f32<<<grid, block, 0, stream>>>(embedding, self_feats, neigh_idx, out, B);
    }
}

// Round 5
// 212.106 us; speedup vs baseline: 1.0205x; 1.0205x over previous
//
#include <hip/hip_runtime.h>

// IntraAgg: out[b] = concat(mean_k E[idx[b,k]], self[b] - mean)
// B=50000, K=32, D=128.
// Phase 1: convert embedding table fp32 -> fp8 e4m3 (OCP) into d_ws.
//          Row shrinks 512B -> 128B = one L2/L3 line per gather.
// Phase 2: gather-mean from fp8 table, 16 lanes/row, 8B/lane loads
//          (16*8B = 128B = full fp8 row, coalesced). HW v_cvt_pk_f32_fp8
//          decode, f32x2 accumulators (v_pk_add_f32).
// Evidence trail:
//   R1: nt stores -> 5.4x HBM write amplification + L3 table eviction. Removed.
//   R2: packed adds neutral -> gather not VALU-bound.
//   R3: 8->16 lanes/row (occupancy 6.1->8 waves/SIMD): -8.4 us -> gather is
//       concurrency-limited on random 128B-line fetches (~3.1 TB/s effective).
//       MEASURED BEST: 212.6 us.
//   R4: explicit load double-buffer pipeline: +3.9 us (neutral/slight harm) ->
//       per-wave issue already fine; at 8-waves/SIMD cap the random-line
//       service rate is the floor. REVERTED here to the R3 artifact.
// Structural floor: ~114 harness (ws/out poison fills) + ~19 convert
// (128MB @ streaming ceiling) + ~13 compulsory streams + ~66 random-line
// fetch (1.6M lines @ ~3.1 TB/s effective). Alternatives all worse:
// bf16 rows = 2 lines/gather; fp4/fp6 don't cut LINE count; scatter
// formulation = nnz*512B RMW >> nnz*128B gather.

constexpr int D = 128;
constexpr int K = 32;
constexpr int ROW_WORDS = D / 4;   // 32 u32 words per fp8 row

typedef float f32x2 __attribute__((ext_vector_type(2)));

// ---------- Phase 1: fp32 -> fp8 e4m3 table conversion ----------
__global__ __launch_bounds__(256) void convert_f32_to_fp8(
    const float* __restrict__ in, unsigned int* __restrict__ out, int n16)
{
    int i = blockIdx.x * blockDim.x + threadIdx.x;   // each thread: 16 floats
    if (i >= n16) return;
    const float4* p = reinterpret_cast<const float4*>(in) + (size_t)i * 4;
    float4 a = p[0], b = p[1], c = p[2], d = p[3];
    unsigned int w0 = 0, w1 = 0, w2 = 0, w3 = 0;
    w0 = __builtin_amdgcn_cvt_pk_fp8_f32(a.x, a.y, w0, false);
    w0 = __builtin_amdgcn_cvt_pk_fp8_f32(a.z, a.w, w0, true);
    w1 = __builtin_amdgcn_cvt_pk_fp8_f32(b.x, b.y, w1, false);
    w1 = __builtin_amdgcn_cvt_pk_fp8_f32(b.z, b.w, w1, true);
    w2 = __builtin_amdgcn_cvt_pk_fp8_f32(c.x, c.y, w2, false);
    w2 = __builtin_amdgcn_cvt_pk_fp8_f32(c.z, c.w, w2, true);
    w3 = __builtin_amdgcn_cvt_pk_fp8_f32(d.x, d.y, w3, false);
    w3 = __builtin_amdgcn_cvt_pk_fp8_f32(d.z, d.w, w3, true);
    uint4 pack; pack.x = w0; pack.y = w1; pack.z = w2; pack.w = w3;
    reinterpret_cast<uint4*>(out)[i] = pack;
}

// ---------- Phase 2: gather-mean, 16 lanes per row (R3 artifact) ----------
__global__ __launch_bounds__(256) void intra_agg_fp8(
    const unsigned int* __restrict__ emb,   // fp8 table, 32 words/row
    const float* __restrict__ self_feats,
    const int*   __restrict__ neighbor_idx,
    float*       __restrict__ out,
    int B)
{
    const int tid  = blockIdx.x * blockDim.x + threadIdx.x;
    const int row  = tid >> 4;          // 16 lanes per row
    const int lane = tid & 15;
    if (row >= B) return;

    // Each lane preloads 2 of the 32 indices; broadcast within 16-lane segment.
    const int* ip = neighbor_idx + (size_t)row * K;
    const int iA = ip[lane];
    const int iB = ip[lane + 16];
    const int cw = lane * 2;            // u32-word column base (2 words = 8 fp8)

    // Lane owns float columns [lane*8, lane*8+8): 4 f32x2 accumulators.
    f32x2 acc[4];
    #pragma unroll
    for (int j = 0; j < 4; ++j) acc[j] = (f32x2){0.f, 0.f};

    #pragma unroll
    for (int k = 0; k < 16; ++k) {
        const int a = __shfl(iA, k, 16);          // idx[row][k]
        const int b = __shfl(iB, k, 16);          // idx[row][k+16]
        const uint2 ea = *reinterpret_cast<const uint2*>(emb + (size_t)a * ROW_WORDS + cw);
        const uint2 eb = *reinterpret_cast<const uint2*>(emb + (size_t)b * ROW_WORDS + cw);
        acc[0] += __builtin_amdgcn_cvt_pk_f32_fp8(ea.x, false);
        acc[1] += __builtin_amdgcn_cvt_pk_f32_fp8(ea.x, true );
        acc[2] += __builtin_amdgcn_cvt_pk_f32_fp8(ea.y, false);
        acc[3] += __builtin_amdgcn_cvt_pk_f32_fp8(ea.y, true );
        acc[0] += __builtin_amdgcn_cvt_pk_f32_fp8(eb.x, false);
        acc[1] += __builtin_amdgcn_cvt_pk_f32_fp8(eb.x, true );
        acc[2] += __builtin_amdgcn_cvt_pk_f32_fp8(eb.y, false);
        acc[3] += __builtin_amdgcn_cvt_pk_f32_fp8(eb.y, true );
    }

    const float inv = 1.0f / (float)K;
    const int c0 = lane * 8;            // float column base (8 floats/lane)
    const float4* sp = reinterpret_cast<const float4*>(self_feats + (size_t)row * D + c0);
    float* orow = out + (size_t)row * (2 * D);
    float4* om = reinterpret_cast<float4*>(orow + c0);
    float4* od = reinterpret_cast<float4*>(orow + D + c0);

    #pragma unroll
    for (int q = 0; q < 2; ++q) {
        float4 m;
        m.x = acc[2*q + 0].x * inv;
        m.y = acc[2*q + 0].y * inv;
        m.z = acc[2*q + 1].x * inv;
        m.w = acc[2*q + 1].y * inv;
        const float4 s = sp[q];
        float4 dd;
        dd.x = s.x - m.x; dd.y = s.y - m.y; dd.z = s.z - m.z; dd.w = s.w - m.w;
        om[q] = m;
        od[q] = dd;
    }
}

// ---------- Fallback fp32 gather (if ws too small) ----------
__global__ __launch_bounds__(256) void intra_agg_f32(
    const float* __restrict__ embedding,
    const float* __restrict__ self_feats,
    const int*   __restrict__ neighbor_idx,
    float*       __restrict__ out,
    int B)
{
    const int tid    = blockIdx.x * blockDim.x + threadIdx.x;
    const int row    = tid >> 5;
    const int lane32 = tid & 31;
    if (row >= B) return;

    const int my_idx = neighbor_idx[(size_t)row * K + lane32];
    const int c = lane32 * 4;

    float4 a0 = {0,0,0,0}, a1 = {0,0,0,0}, a2 = {0,0,0,0}, a3 = {0,0,0,0};
    #pragma unroll
    for (int k = 0; k < K; k += 4) {
        const int i0 = __shfl(my_idx, k + 0, 32);
        const int i1 = __shfl(my_idx, k + 1, 32);
        const int i2 = __shfl(my_idx, k + 2, 32);
        const int i3 = __shfl(my_idx, k + 3, 32);
        const float4 e0 = *reinterpret_cast<const float4*>(embedding + (size_t)i0 * D + c);
        const float4 e1 = *reinterpret_cast<const float4*>(embedding + (size_t)i1 * D + c);
        const float4 e2 = *reinterpret_cast<const float4*>(embedding + (size_t)i2 * D + c);
        const float4 e3 = *reinterpret_cast<const float4*>(embedding + (size_t)i3 * D + c);
        a0.x += e0.x; a0.y += e0.y; a0.z += e0.z; a0.w += e0.w;
        a1.x += e1.x; a1.y += e1.y; a1.z += e1.z; a1.w += e1.w;
        a2.x += e2.x; a2.y += e2.y; a2.z += e2.z; a2.w += e2.w;
        a3.x += e3.x; a3.y += e3.y; a3.z += e3.z; a3.w += e3.w;
    }

    const float inv = 1.0f / (float)K;
    float4 mean;
    mean.x = (a0.x + a1.x + a2.x + a3.x) * inv;
    mean.y = (a0.y + a1.y + a2.y + a3.y) * inv;
    mean.z = (a0.z + a1.z + a2.z + a3.z) * inv;
    mean.w = (a0.w + a1.w + a2.w + a3.w) * inv;

    const float4 self = *reinterpret_cast<const float4*>(self_feats + (size_t)row * D + c);
    float4 diff;
    diff.x = self.x - mean.x; diff.y = self.y - mean.y;
    diff.z = self.z - mean.z; diff.w = self.w - mean.w;

    float* orow = out + (size_t)row * (2 * D);
    *reinterpret_cast<float4*>(orow + c)     = mean;
    *reinterpret_cast<float4*>(orow + D + c) = diff;
}

extern "C" void kernel_launch(void* const* d_in, const int* in_sizes, int n_in,
                              void* d_out, int out_size, void* d_ws, size_t ws_size,
                              hipStream_t stream) {
    const float* embedding  = (const float*)d_in[0];
    const float* self_feats = (const float*)d_in[1];
    const int*   neigh_idx  = (const int*)d_in[2];
    float* out = (float*)d_out;

    const int n_embed_elems = in_sizes[0];          // 200000*128
    const int B = in_sizes[1] / D;                  // 50000
    const size_t fp8_bytes = (size_t)n_embed_elems; // 1 byte/elem

    if (ws_size >= fp8_bytes) {
        unsigned int* emb8 = (unsigned int*)d_ws;
        // Phase 1: convert table (16 floats / thread)
        {
            const int n16 = n_embed_elems / 16;
            const int block = 256;
            const int grid = (n16 + block - 1) / block;
            convert_f32_to_fp8<<<grid, block, 0, stream>>>(embedding, emb8, n16);
        }
        // Phase 2: gather-mean (16 lanes / row)
        {
            const long long total_threads = (long long)B * 16;
            const int block = 256;
            const int grid = (int)((total_threads + block - 1) / block);
            intra_agg_fp8<<<grid, block, 0, stream>>>(emb8, self_feats, neigh_idx, out, B);
        }
    } else {
        const long long total_threads = (long long)B * 32;
        const int block = 256;
        const int grid = (int)((total_threads + block - 1) / block);
        intra_agg_f32<<<grid, block, 0, stream>>>(embedding, self_feats, neigh_idx, out, B);
    }
}